// Round 16
// baseline (669.989 us; speedup 1.0000x reference)
//
#include <hip/hip_runtime.h>
#include <math.h>

#define N_NODES 50000
#define N_EDGES 800000
#define FIN     16
#define EDIM    4
#define NGRAPH  500
#define LATD    32
#define HID     64
#define C1      192   // 3*HID
#define H1      3
#define EPS_BN  1e-5f
#define NEGSL   0.2f
#define ROWS1   128
#define ROWS2   128
#define PAD2    196   // A-tile row stride (192 + 4): keeps 16B align, spreads banks

__device__ __forceinline__ float wred(float v) {
    #pragma unroll
    for (int o = 32; o > 0; o >>= 1) v += __shfl_xor(v, o, 64);
    return v;
}
__device__ __forceinline__ float wmax(float v) {
    #pragma unroll
    for (int o = 32; o > 0; o >>= 1) v = fmaxf(v, __shfl_xor(v, o, 64));
    return v;
}

// ---------- tiny precompute: V1[4x3] at V[0..11], V2[4] at V[12..15] ----------
__global__ void k_v(const float* __restrict__ We1, const float* __restrict__ a1e,
                    const float* __restrict__ We2, const float* __restrict__ a2e,
                    float* __restrict__ V) {
    int t = threadIdx.x;
    if (t < 12) {
        int k = t / 3, h = t % 3;
        float s = 0.f;
        for (int c = 0; c < HID; ++c) s += We1[k*C1 + h*HID + c] * a1e[h*HID + c];
        V[k*3 + h] = s;
    } else if (t < 16) {
        int k = t - 12;
        float s = 0.f;
        for (int c = 0; c < HID; ++c) s += We2[k*HID + c] * a2e[c];
        V[12 + k] = s;
    }
}

// ---------- layer-1 node transform + attention scalars: wave per (n,h) ----------
__global__ void k_h1att(const float* __restrict__ x, const float* __restrict__ W1,
                        const float* __restrict__ a1s, const float* __restrict__ a1d,
                        float* __restrict__ h1, float* __restrict__ asrc,
                        float* __restrict__ adst) {
    int w = blockIdx.x * (blockDim.x >> 6) + (threadIdx.x >> 6);
    int lane = threadIdx.x & 63;
    if (w >= N_NODES * H1) return;
    int n = w / H1, h = w % H1;
    int c = h*HID + lane;
    const float* xr = x + n * FIN;
    float acc = 0.f;
    #pragma unroll
    for (int k = 0; k < FIN; ++k) acc += xr[k] * W1[k*C1 + c];
    h1[n*C1 + c] = acc;
    float s = wred(acc * a1s[c]);
    float d = wred(acc * a1d[c]);
    if (lane == 0) { asrc[n*H1 + h] = s; adst[n*H1 + h] = d; }
}

// ---------- CSR build ----------
__global__ void k_deg(const int* __restrict__ ei, int* __restrict__ deg) {
    int e = blockIdx.x * blockDim.x + threadIdx.x;
    if (e >= N_EDGES) return;
    atomicAdd(&deg[ei[N_EDGES + e]], 1);
}

// single-block scan of deg[N] -> row[N+1]; also initializes cursor = row[0..N)
// NOTE: deg must be 16B-aligned (int4 loads) — Z0 is aligned in kernel_launch.
__global__ void k_scan(const int* __restrict__ deg, int* __restrict__ row,
                       int* __restrict__ cur) {
    __shared__ int part[1024];
    const int T = 1024, CH = 52;
    int t = threadIdx.x;
    int base = t * CH;
    int s = 0;
    if (base < N_NODES) {
        int hi = min(base + CH, N_NODES);
        int i = base;
        for (; i + 3 < hi; i += 4) { int4 v = *(const int4*)(deg + i); s += v.x + v.y + v.z + v.w; }
        for (; i < hi; ++i) s += deg[i];
    }
    part[t] = s;
    __syncthreads();
    for (int off = 1; off < T; off <<= 1) {
        int v = (t >= off) ? part[t - off] : 0;
        __syncthreads();
        part[t] += v;
        __syncthreads();
    }
    int run = (t == 0) ? 0 : part[t - 1];
    if (base <= N_NODES) {
        int hi = min(base + CH, N_NODES + 1);
        for (int i = base; i < hi; ++i) {
            row[i] = run;
            if (i < N_NODES) { cur[i] = run; run += deg[i]; }
        }
    }
}

// ---------- CSR permutation: scatter ONLY eperm[j]=e (4B payload) ----------
__global__ void k_perm(const int* __restrict__ ei, int* __restrict__ cur,
                       int* __restrict__ eperm) {
    int e = blockIdx.x * blockDim.x + threadIdx.x;
    if (e >= N_EDGES) return;
    int d = ei[N_EDGES + e];
    int j = atomicAdd(&cur[d], 1);
    eperm[j] = e;
}

// ---------- coalesced fill: thread per CSR slot j ----------
__global__ void k_fill2(const int* __restrict__ ei, const float* __restrict__ ea,
                        const int* __restrict__ eperm,
                        const float* __restrict__ asrc, const float* __restrict__ adst,
                        const float* __restrict__ V,
                        int* __restrict__ srcp, int* __restrict__ dstp,
                        float* __restrict__ alpha1, float* __restrict__ ae2) {
    int j = blockIdx.x * blockDim.x + threadIdx.x;
    if (j >= N_EDGES) return;
    int e = eperm[j];
    int s = ei[e], d = ei[N_EDGES + e];
    srcp[j] = s;
    dstp[j] = d;
    float4 ev = ((const float4*)ea)[e];
    ae2[j] = ev.x*V[12] + ev.y*V[13] + ev.z*V[14] + ev.w*V[15];
    #pragma unroll
    for (int h = 0; h < H1; ++h) {
        float a = asrc[s*H1 + h] + adst[d*H1 + h]
                + ev.x*V[h] + ev.y*V[3+h] + ev.z*V[6+h] + ev.w*V[9+h];
        a = a > 0.f ? a : NEGSL * a;
        alpha1[(size_t)h*N_EDGES + j] = a;
    }
}

// ---------- layer-1 fused softmax + aggregate: wave per (dst, head) ----------
// slot-parallel gather: lane = slot*16 + c4; each lane gathers float4 (4 channels)
__global__ void k_agg1(const int* __restrict__ row, const int* __restrict__ srcp,
                       const float* __restrict__ alpha, const float* __restrict__ h1,
                       float* __restrict__ out1) {
    __shared__ int2 pairs[4][64];
    int wid = threadIdx.x >> 6;
    int lane = threadIdx.x & 63;
    int w = blockIdx.x * 4 + wid;
    if (w >= N_NODES * H1) return;
    int d = w / H1, h = w % H1;
    int r0 = row[d], r1 = row[d + 1];
    const float* ap = alpha + (size_t)h*N_EDGES;

    float m = -1e30f;
    for (int j = r0 + lane; j < r1; j += 64) m = fmaxf(m, ap[j]);
    m = wmax(m);

    float ssum = 0.f;
    for (int j = r0 + lane; j < r1; j += 64) ssum += __expf(ap[j] - m);
    ssum = wred(ssum);
    float inv = 1.f / (ssum + 1e-16f);

    int slot = lane >> 4, c4 = lane & 15;
    const float* hbase = h1 + h*HID + c4*4;
    float4 acc = make_float4(0.f, 0.f, 0.f, 0.f);
    for (int base = r0; base < r1; base += 64) {
        int n = min(64, r1 - base);
        if (lane < n) {
            float cf = __expf(ap[base + lane] - m) * inv;
            pairs[wid][lane] = make_int2(srcp[base + lane], __float_as_int(cf));
        }
        #pragma unroll 4
        for (int idx = slot; idx < n; idx += 4) {
            int2 p = pairs[wid][idx];
            float cf = __int_as_float(p.y);
            const float4 hv = *(const float4*)(hbase + (size_t)p.x * C1);
            acc.x += cf * hv.x; acc.y += cf * hv.y;
            acc.z += cf * hv.z; acc.w += cf * hv.w;
        }
    }
    #pragma unroll
    for (int o = 16; o < 64; o <<= 1) {
        acc.x += __shfl_xor(acc.x, o, 64);
        acc.y += __shfl_xor(acc.y, o, 64);
        acc.z += __shfl_xor(acc.z, o, 64);
        acc.w += __shfl_xor(acc.w, o, 64);
    }
    if (lane < 16)
        *(float4*)(out1 + (size_t)d*C1 + h*HID + c4*4) = acc;
}

// ---------- layer-1: +bias, ELU (in place), BN partial stats ----------
__global__ void k_stats1(float* __restrict__ out, const float* __restrict__ b,
                         float* __restrict__ stats) {
    int c = threadIdx.x;                 // 0..191
    int r0 = blockIdx.x * ROWS1;
    int r1 = min(r0 + ROWS1, N_NODES);
    float bc = b[c];
    float s = 0.f, ss = 0.f;
    for (int r = r0; r < r1; ++r) {
        float v = out[r*C1 + c] + bc;
        v = v > 0.f ? v : expm1f(v);
        out[r*C1 + c] = v;
        s += v; ss += v * v;
    }
    atomicAdd(&stats[c], s);
    atomicAdd(&stats[C1 + c], ss);
}

__global__ void k_fin1(float* __restrict__ stats) {
    int c = threadIdx.x;
    if (c < C1) {
        float mu  = stats[c] / (float)N_NODES;
        float var = stats[C1 + c] / (float)N_NODES - mu * mu;
        stats[2*C1 + c] = mu;
        stats[3*C1 + c] = rsqrtf(var + EPS_BN);
    }
}

__global__ void k_norm1(float* __restrict__ out, const float* __restrict__ g,
                        const float* __restrict__ be, const float* __restrict__ stats) {
    int i = blockIdx.x * blockDim.x + threadIdx.x;
    if (i >= N_NODES * C1) return;
    int c = i % C1;
    out[i] = g[c] * (out[i] - stats[2*C1 + c]) * stats[3*C1 + c] + be[c];
}

// ---------- layer-2 node transform: tiled GEMM [64 nodes x 64 cols]/block ----------
__global__ void __launch_bounds__(256) k_h2(
        const float* __restrict__ h1bn, const float* __restrict__ W2,
        const float* __restrict__ a2s, const float* __restrict__ a2d,
        float* __restrict__ h2, float* __restrict__ asrc, float* __restrict__ adst) {
    __shared__ float As[64 * PAD2];          // ~50 KB
    int tid = threadIdx.x;
    int nb = blockIdx.x * 64;
    const float4* src = (const float4*)(h1bn + (size_t)nb * C1);
    #pragma unroll
    for (int j = 0; j < 12; ++j) {
        int idx = tid + j * 256;             // float4 index 0..3071
        int n = idx / 48, kq = idx - n * 48;
        *(float4*)(As + n * PAD2 + kq * 4) = src[idx];
    }
    __syncthreads();

    int lane = tid & 63;
    int tx = lane & 15, tyw = lane >> 4;
    int ty = (tid >> 6) * 4 + tyw;           // 0..15
    int r0 = ty * 4;                          // A-tile row base (4 nodes)
    const float* wp = W2 + tx * 4;

    float4 acc0 = {0,0,0,0}, acc1 = {0,0,0,0}, acc2 = {0,0,0,0}, acc3 = {0,0,0,0};
    #pragma unroll 4
    for (int k = 0; k < C1; ++k) {
        float4 w4 = *(const float4*)(wp + k * HID);
        float a0 = As[(r0+0)*PAD2 + k];
        float a1 = As[(r0+1)*PAD2 + k];
        float a2 = As[(r0+2)*PAD2 + k];
        float a3 = As[(r0+3)*PAD2 + k];
        acc0.x += a0*w4.x; acc0.y += a0*w4.y; acc0.z += a0*w4.z; acc0.w += a0*w4.w;
        acc1.x += a1*w4.x; acc1.y += a1*w4.y; acc1.z += a1*w4.z; acc1.w += a1*w4.w;
        acc2.x += a2*w4.x; acc2.y += a2*w4.y; acc2.z += a2*w4.z; acc2.w += a2*w4.w;
        acc3.x += a3*w4.x; acc3.y += a3*w4.y; acc3.z += a3*w4.z; acc3.w += a3*w4.w;
    }

    float4 s4 = *(const float4*)(a2s + tx*4);
    float4 d4 = *(const float4*)(a2d + tx*4);

    #define H2_EPI(ACC, I)                                                        \
    {                                                                             \
        int n = nb + r0 + (I);                                                    \
        float s = ACC.x*s4.x + ACC.y*s4.y + ACC.z*s4.z + ACC.w*s4.w;              \
        float d = ACC.x*d4.x + ACC.y*d4.y + ACC.z*d4.z + ACC.w*d4.w;              \
        s += __shfl_xor(s, 1, 64); s += __shfl_xor(s, 2, 64);                     \
        s += __shfl_xor(s, 4, 64); s += __shfl_xor(s, 8, 64);                     \
        d += __shfl_xor(d, 1, 64); d += __shfl_xor(d, 2, 64);                     \
        d += __shfl_xor(d, 4, 64); d += __shfl_xor(d, 8, 64);                     \
        if (n < N_NODES) {                                                        \
            *(float4*)(h2 + (size_t)n*HID + tx*4) = ACC;                          \
            if (tx == 0) { asrc[n] = s; adst[n] = d; }                            \
        }                                                                         \
    }
    H2_EPI(acc0, 0)
    H2_EPI(acc1, 1)
    H2_EPI(acc2, 2)
    H2_EPI(acc3, 3)
    #undef H2_EPI
}

// ---------- layer-2 alpha: thread per CSR slot ----------
__global__ void k_alpha2(const int* __restrict__ srcp, const int* __restrict__ dstp,
                         const float* __restrict__ ae2,
                         const float* __restrict__ asrc, const float* __restrict__ adst,
                         float* __restrict__ alpha2) {
    int j = blockIdx.x * blockDim.x + threadIdx.x;
    if (j >= N_EDGES) return;
    float a = asrc[srcp[j]] + adst[dstp[j]] + ae2[j];
    a = a > 0.f ? a : NEGSL * a;
    alpha2[j] = a;
}

// ---------- layer-2 fused softmax + aggregate: wave per dst, slot-parallel ----------
__global__ void k_agg2(const int* __restrict__ row, const int* __restrict__ srcp,
                       const float* __restrict__ alpha, const float* __restrict__ h2,
                       float* __restrict__ out2) {
    __shared__ int2 pairs[4][64];
    int wid = threadIdx.x >> 6;
    int lane = threadIdx.x & 63;
    int d = blockIdx.x * 4 + wid;
    if (d >= N_NODES) return;
    int r0 = row[d], r1 = row[d + 1];

    float m = -1e30f;
    for (int j = r0 + lane; j < r1; j += 64) m = fmaxf(m, alpha[j]);
    m = wmax(m);

    float ssum = 0.f;
    for (int j = r0 + lane; j < r1; j += 64) ssum += __expf(alpha[j] - m);
    ssum = wred(ssum);
    float inv = 1.f / (ssum + 1e-16f);

    int slot = lane >> 4, c4 = lane & 15;
    const float* hbase = h2 + c4*4;
    float4 acc = make_float4(0.f, 0.f, 0.f, 0.f);
    for (int base = r0; base < r1; base += 64) {
        int n = min(64, r1 - base);
        if (lane < n) {
            float cf = __expf(alpha[base + lane] - m) * inv;
            pairs[wid][lane] = make_int2(srcp[base + lane], __float_as_int(cf));
        }
        #pragma unroll 4
        for (int idx = slot; idx < n; idx += 4) {
            int2 p = pairs[wid][idx];
            float cf = __int_as_float(p.y);
            const float4 hv = *(const float4*)(hbase + (size_t)p.x * HID);
            acc.x += cf * hv.x; acc.y += cf * hv.y;
            acc.z += cf * hv.z; acc.w += cf * hv.w;
        }
    }
    #pragma unroll
    for (int o = 16; o < 64; o <<= 1) {
        acc.x += __shfl_xor(acc.x, o, 64);
        acc.y += __shfl_xor(acc.y, o, 64);
        acc.z += __shfl_xor(acc.z, o, 64);
        acc.w += __shfl_xor(acc.w, o, 64);
    }
    if (lane < 16)
        *(float4*)(out2 + (size_t)d*HID + c4*4) = acc;
}

// ---------- layer-2: +bias, ELU, BN stats (64 cols, 4 row-replicas) ----------
__global__ void k_stats2(float* __restrict__ out, const float* __restrict__ b,
                         float* __restrict__ stats) {
    int c = threadIdx.x & 63;
    int rep = threadIdx.x >> 6;
    int base = blockIdx.x * ROWS2;
    int r1 = min(base + ROWS2, N_NODES);
    float bc = b[c];
    float s = 0.f, ss = 0.f;
    for (int r = base + rep; r < r1; r += 4) {
        float v = out[r*HID + c] + bc;
        v = v > 0.f ? v : expm1f(v);
        out[r*HID + c] = v;
        s += v; ss += v * v;
    }
    __shared__ float ls[256], lss[256];
    ls[threadIdx.x] = s; lss[threadIdx.x] = ss;
    __syncthreads();
    if (rep == 0) {
        s  = ls[c]  + ls[64+c]  + ls[128+c]  + ls[192+c];
        ss = lss[c] + lss[64+c] + lss[128+c] + lss[192+c];
        atomicAdd(&stats[768 + c], s);
        atomicAdd(&stats[832 + c], ss);
    }
}

__global__ void k_fin2(float* __restrict__ stats) {
    int c = threadIdx.x;
    if (c < HID) {
        float mu  = stats[768 + c] / (float)N_NODES;
        float var = stats[832 + c] / (float)N_NODES - mu * mu;
        stats[896 + c] = mu;
        stats[960 + c] = rsqrtf(var + EPS_BN);
    }
}

// ---------- normalize + gate + graph pooling (wave per node) ----------
__global__ void k_final(const float* __restrict__ out2, const float* __restrict__ g,
                        const float* __restrict__ be, const float* __restrict__ stats,
                        const float* __restrict__ wA, const float* __restrict__ bA,
                        const int* __restrict__ batch, float* __restrict__ hg) {
    int n = blockIdx.x * (blockDim.x >> 6) + (threadIdx.x >> 6);
    int lane = threadIdx.x & 63;
    if (n >= N_NODES) return;
    float v = out2[n*HID + lane];
    v = g[lane] * (v - stats[896 + lane]) * stats[960 + lane] + be[lane];
    float gs = wred(v * wA[lane]);
    float gate = 1.f / (1.f + expf(-(gs + bA[0])));
    atomicAdd(&hg[batch[n]*HID + lane], v * gate);
}

// ---------- output GEMMs: [500,64] @ [64,32] x2 ----------
__global__ void k_out(const float* __restrict__ hg, const float* __restrict__ wMu,
                      const float* __restrict__ bMu, const float* __restrict__ wLv,
                      const float* __restrict__ bLv, float* __restrict__ out) {
    __shared__ float rowv[HID];
    int gid = blockIdx.x, t = threadIdx.x;
    rowv[t] = hg[gid*HID + t];
    __syncthreads();
    if (t < LATD) {
        float s = 0.f;
        #pragma unroll
        for (int k = 0; k < HID; ++k) s += rowv[k] * wMu[k*LATD + t];
        out[gid*LATD + t] = s + bMu[t];
    } else {
        int c = t - LATD;
        float s = 0.f;
        #pragma unroll
        for (int k = 0; k < HID; ++k) s += rowv[k] * wLv[k*LATD + c];
        out[NGRAPH*LATD + gid*LATD + c] = s + bLv[c];
    }
}

extern "C" void kernel_launch(void* const* d_in, const int* in_sizes, int n_in,
                              void* d_out, int out_size, void* d_ws, size_t ws_size,
                              hipStream_t stream) {
    const float* x   = (const float*)d_in[0];
    const int*   ei  = (const int*)  d_in[1];
    const float* ea  = (const float*)d_in[2];
    const int*   bat = (const int*)  d_in[3];
    const float* W1  = (const float*)d_in[4];
    const float* a1s = (const float*)d_in[5];
    const float* a1d = (const float*)d_in[6];
    const float* We1 = (const float*)d_in[7];
    const float* a1e = (const float*)d_in[8];
    const float* b1  = (const float*)d_in[9];
    const float* g1  = (const float*)d_in[10];
    const float* be1 = (const float*)d_in[11];
    const float* W2  = (const float*)d_in[12];
    const float* a2s = (const float*)d_in[13];
    const float* a2d = (const float*)d_in[14];
    const float* We2 = (const float*)d_in[15];
    const float* a2e = (const float*)d_in[16];
    const float* b2  = (const float*)d_in[17];
    const float* g2  = (const float*)d_in[18];
    const float* be2 = (const float*)d_in[19];
    const float* wA  = (const float*)d_in[20];
    const float* bA  = (const float*)d_in[21];
    const float* wMu = (const float*)d_in[22];
    const float* bMu = (const float*)d_in[23];
    const float* wLv = (const float*)d_in[24];
    const float* bLv = (const float*)d_in[25];
    float* out = (float*)d_out;
    float* w = (float*)d_ws;

    // ---- workspace layout (floats) ----
    const size_t oH1   = 0;                             // h1 [N*192]; later h2 [N*64]
    const size_t oO1   = oH1  + (size_t)N_NODES*C1;     // out1 [N*192]; later out2 [N*64]
    const size_t oAS   = oO1  + (size_t)N_NODES*C1;     // asrc [N*3] (layer2: [N])
    const size_t oAD   = oAS  + (size_t)N_NODES*H1;     // adst [N*3]
    const size_t oSRC  = oAD  + (size_t)N_NODES*H1;     // srcp [E] int
    const size_t oDST  = oSRC + (size_t)N_EDGES;        // dstp [E] int
    const size_t oAE2  = oDST + (size_t)N_EDGES;        // ae2 [E]
    const size_t oAL   = oAE2 + (size_t)N_EDGES;        // alpha1 [3E] (layer2: [E] plane0)
    const size_t oROW  = oAL  + (size_t)N_EDGES*H1;     // row [N+1] int
    const size_t oCUR  = oROW + (size_t)(N_NODES+1);    // cursor [N] int (written by scan)
    const size_t oPERM = oCUR + (size_t)N_NODES;        // eperm [E] int
    const size_t Z0raw = oPERM + (size_t)N_EDGES;
    const size_t Z0    = (Z0raw + 3) & ~(size_t)3;      // 16B-align (int4 loads on deg)
    const size_t oDEG  = Z0;                            // deg [N] int
    const size_t oST   = oDEG + (size_t)N_NODES;        // stats [1024]
    const size_t oHG   = oST  + 1024;                   // hg [500*64]
    const size_t oV    = oHG  + (size_t)NGRAPH*HID;     // V [16] (pad 64)
    const size_t oEND  = oV   + 64;

    hipMemsetAsync(w + Z0, 0, (oEND - Z0) * sizeof(float), stream);

    k_v<<<1, 64, 0, stream>>>(We1, a1e, We2, a2e, w + oV);
    k_h1att<<<(N_NODES*H1 + 3)/4, 256, 0, stream>>>(x, W1, a1s, a1d,
                                                    w + oH1, w + oAS, w + oAD);
    k_deg<<<(N_EDGES + 255)/256, 256, 0, stream>>>(ei, (int*)(w + oDEG));
    k_scan<<<1, 1024, 0, stream>>>((int*)(w + oDEG), (int*)(w + oROW), (int*)(w + oCUR));
    k_perm<<<(N_EDGES + 255)/256, 256, 0, stream>>>(ei, (int*)(w + oCUR), (int*)(w + oPERM));
    k_fill2<<<(N_EDGES + 255)/256, 256, 0, stream>>>(ei, ea, (int*)(w + oPERM),
                                                     w + oAS, w + oAD, w + oV,
                                                     (int*)(w + oSRC), (int*)(w + oDST),
                                                     w + oAL, w + oAE2);

    k_agg1<<<(N_NODES*H1 + 3)/4, 256, 0, stream>>>((int*)(w + oROW), (int*)(w + oSRC),
                                                   w + oAL, w + oH1, w + oO1);
    k_stats1<<<(N_NODES + ROWS1 - 1)/ROWS1, C1, 0, stream>>>(w + oO1, b1, w + oST);
    k_fin1<<<1, C1, 0, stream>>>(w + oST);
    k_norm1<<<(N_NODES*C1 + 255)/256, 256, 0, stream>>>(w + oO1, g1, be1, w + oST);

    k_h2<<<(N_NODES + 63)/64, 256, 0, stream>>>(w + oO1, W2, a2s, a2d,
                                                w + oH1, w + oAS, w + oAD);
    k_alpha2<<<(N_EDGES + 255)/256, 256, 0, stream>>>((int*)(w + oSRC), (int*)(w + oDST),
                                                      w + oAE2, w + oAS, w + oAD, w + oAL);
    k_agg2<<<(N_NODES + 3)/4, 256, 0, stream>>>((int*)(w + oROW), (int*)(w + oSRC),
                                                w + oAL, w + oH1, w + oO1);
    k_stats2<<<(N_NODES + ROWS2 - 1)/ROWS2, 256, 0, stream>>>(w + oO1, b2, w + oST);
    k_fin2<<<1, HID, 0, stream>>>(w + oST);
    k_final<<<(N_NODES + 3)/4, 256, 0, stream>>>(w + oO1, g2, be2, w + oST, wA, bA, bat, w + oHG);
    k_out<<<NGRAPH, HID, 0, stream>>>(w + oHG, wMu, bMu, wLv, bLv, out);
}

// Round 17
// 584.466 us; speedup vs baseline: 1.1463x; 1.1463x over previous
//
#include <hip/hip_runtime.h>
#include <math.h>

#define N_NODES 50000
#define N_EDGES 800000
#define FIN     16
#define EDIM    4
#define NGRAPH  500
#define LATD    32
#define HID     64
#define C1      192   // 3*HID
#define H1      3
#define EPS_BN  1e-5f
#define NEGSL   0.2f
#define ROWS1   128
#define ROWS2   128
#define PAD2    196   // A-tile row stride (192 + 4): keeps 16B align, spreads banks
#define SCHUNK  512
#define NSBLK   ((N_NODES + SCHUNK - 1) / SCHUNK)   // 98

__device__ __forceinline__ float wred(float v) {
    #pragma unroll
    for (int o = 32; o > 0; o >>= 1) v += __shfl_xor(v, o, 64);
    return v;
}
__device__ __forceinline__ float wmax(float v) {
    #pragma unroll
    for (int o = 32; o > 0; o >>= 1) v = fmaxf(v, __shfl_xor(v, o, 64));
    return v;
}

// ---------- tiny precompute: V1[4x3] at V[0..11], V2[4] at V[12..15] ----------
__global__ void k_v(const float* __restrict__ We1, const float* __restrict__ a1e,
                    const float* __restrict__ We2, const float* __restrict__ a2e,
                    float* __restrict__ V) {
    int t = threadIdx.x;
    if (t < 12) {
        int k = t / 3, h = t % 3;
        float s = 0.f;
        for (int c = 0; c < HID; ++c) s += We1[k*C1 + h*HID + c] * a1e[h*HID + c];
        V[k*3 + h] = s;
    } else if (t < 16) {
        int k = t - 12;
        float s = 0.f;
        for (int c = 0; c < HID; ++c) s += We2[k*HID + c] * a2e[c];
        V[12 + k] = s;
    }
}

// ---------- layer-1 node transform + attention scalars: wave per (n,h) ----------
__global__ void k_h1att(const float* __restrict__ x, const float* __restrict__ W1,
                        const float* __restrict__ a1s, const float* __restrict__ a1d,
                        float* __restrict__ h1, float* __restrict__ asrc,
                        float* __restrict__ adst) {
    int w = blockIdx.x * (blockDim.x >> 6) + (threadIdx.x >> 6);
    int lane = threadIdx.x & 63;
    if (w >= N_NODES * H1) return;
    int n = w / H1, h = w % H1;
    int c = h*HID + lane;
    const float* xr = x + n * FIN;
    float acc = 0.f;
    #pragma unroll
    for (int k = 0; k < FIN; ++k) acc += xr[k] * W1[k*C1 + c];
    h1[n*C1 + c] = acc;
    float s = wred(acc * a1s[c]);
    float d = wred(acc * a1d[c]);
    if (lane == 0) { asrc[n*H1 + h] = s; adst[n*H1 + h] = d; }
}

// ---------- CSR build ----------
__global__ void k_deg(const int* __restrict__ ei, int* __restrict__ deg) {
    int e = blockIdx.x * blockDim.x + threadIdx.x;
    if (e >= N_EDGES) return;
    atomicAdd(&deg[ei[N_EDGES + e]], 1);
}

// ---------- hierarchical scan: pass A — block sums (512 deg / block) ----------
__global__ void k_scanA(const int* __restrict__ deg, int* __restrict__ bsum) {
    __shared__ int wtot[4];
    int t = threadIdx.x, b = blockIdx.x;
    int i0 = b * SCHUNK + t * 2;
    int v = 0;
    if (i0 + 1 < N_NODES) { int2 p = *(const int2*)(deg + i0); v = p.x + p.y; }
    else if (i0 < N_NODES) v = deg[i0];
    #pragma unroll
    for (int o = 32; o > 0; o >>= 1) v += __shfl_xor(v, o, 64);
    if ((t & 63) == 0) wtot[t >> 6] = v;
    __syncthreads();
    if (t == 0) bsum[b] = wtot[0] + wtot[1] + wtot[2] + wtot[3];
}

// ---------- pass B — scan 98 block sums (1 block) ----------
__global__ void k_scanB(const int* __restrict__ bsum, int* __restrict__ boff,
                        int* __restrict__ row) {
    __shared__ int w0tot;
    int t = threadIdx.x;
    int v = (t < NSBLK) ? bsum[t] : 0;
    int inc = v;
    int lane = t & 63;
    #pragma unroll
    for (int o = 1; o < 64; o <<= 1) {
        int n = __shfl_up(inc, o, 64);
        if (lane >= o) inc += n;
    }
    if (t == 63) w0tot = inc;
    __syncthreads();
    int off = (t >= 64) ? w0tot : 0;
    if (t < NSBLK) boff[t] = inc - v + off;
    if (t == 0) row[N_NODES] = N_EDGES;   // total degree == edge count
}

// ---------- pass C — per-element exclusive prefix; writes row + cur ----------
__global__ void k_scanC(const int* __restrict__ deg, const int* __restrict__ boff,
                        int* __restrict__ row, int* __restrict__ cur) {
    __shared__ int wtot[4];
    int t = threadIdx.x, b = blockIdx.x;
    int i0 = b * SCHUNK + t * 2;
    int d0 = 0, d1 = 0;
    if (i0 + 1 < N_NODES) { int2 p = *(const int2*)(deg + i0); d0 = p.x; d1 = p.y; }
    else if (i0 < N_NODES) d0 = deg[i0];
    int ps = d0 + d1;
    int inc = ps;
    int lane = t & 63, wid = t >> 6;
    #pragma unroll
    for (int o = 1; o < 64; o <<= 1) {
        int n = __shfl_up(inc, o, 64);
        if (lane >= o) inc += n;
    }
    if (lane == 63) wtot[wid] = inc;
    __syncthreads();
    int woff = 0;
    for (int ww = 0; ww < wid; ++ww) woff += wtot[ww];
    int ex = boff[b] + woff + inc - ps;
    if (i0 < N_NODES)     { row[i0]   = ex;      cur[i0]   = ex;      }
    if (i0 + 1 < N_NODES) { row[i0+1] = ex + d0; cur[i0+1] = ex + d0; }
}

// ---------- CSR permutation: scatter ONLY eperm[j]=e (4B payload) ----------
__global__ void k_perm(const int* __restrict__ ei, int* __restrict__ cur,
                       int* __restrict__ eperm) {
    int e = blockIdx.x * blockDim.x + threadIdx.x;
    if (e >= N_EDGES) return;
    int d = ei[N_EDGES + e];
    int j = atomicAdd(&cur[d], 1);
    eperm[j] = e;
}

// ---------- coalesced fill: thread per CSR slot j ----------
__global__ void k_fill2(const int* __restrict__ ei, const float* __restrict__ ea,
                        const int* __restrict__ eperm,
                        const float* __restrict__ asrc, const float* __restrict__ adst,
                        const float* __restrict__ V,
                        int* __restrict__ srcp, int* __restrict__ dstp,
                        float* __restrict__ alpha1, float* __restrict__ ae2) {
    int j = blockIdx.x * blockDim.x + threadIdx.x;
    if (j >= N_EDGES) return;
    int e = eperm[j];
    int s = ei[e], d = ei[N_EDGES + e];
    srcp[j] = s;
    dstp[j] = d;
    float4 ev = ((const float4*)ea)[e];
    ae2[j] = ev.x*V[12] + ev.y*V[13] + ev.z*V[14] + ev.w*V[15];
    #pragma unroll
    for (int h = 0; h < H1; ++h) {
        float a = asrc[s*H1 + h] + adst[d*H1 + h]
                + ev.x*V[h] + ev.y*V[3+h] + ev.z*V[6+h] + ev.w*V[9+h];
        a = a > 0.f ? a : NEGSL * a;
        alpha1[(size_t)h*N_EDGES + j] = a;
    }
}

// ---------- layer-1 fused softmax + aggregate: wave per (dst, head) ----------
// slot-parallel gather: lane = slot*16 + c4; each lane gathers float4 (4 channels)
__global__ void k_agg1(const int* __restrict__ row, const int* __restrict__ srcp,
                       const float* __restrict__ alpha, const float* __restrict__ h1,
                       float* __restrict__ out1) {
    __shared__ int2 pairs[4][64];
    int wid = threadIdx.x >> 6;
    int lane = threadIdx.x & 63;
    int w = blockIdx.x * 4 + wid;
    if (w >= N_NODES * H1) return;
    int d = w / H1, h = w % H1;
    int r0 = row[d], r1 = row[d + 1];
    const float* ap = alpha + (size_t)h*N_EDGES;

    float m = -1e30f;
    for (int j = r0 + lane; j < r1; j += 64) m = fmaxf(m, ap[j]);
    m = wmax(m);

    float ssum = 0.f;
    for (int j = r0 + lane; j < r1; j += 64) ssum += __expf(ap[j] - m);
    ssum = wred(ssum);
    float inv = 1.f / (ssum + 1e-16f);

    int slot = lane >> 4, c4 = lane & 15;
    const float* hbase = h1 + h*HID + c4*4;
    float4 acc = make_float4(0.f, 0.f, 0.f, 0.f);
    for (int base = r0; base < r1; base += 64) {
        int n = min(64, r1 - base);
        if (lane < n) {
            float cf = __expf(ap[base + lane] - m) * inv;
            pairs[wid][lane] = make_int2(srcp[base + lane], __float_as_int(cf));
        }
        #pragma unroll 4
        for (int idx = slot; idx < n; idx += 4) {
            int2 p = pairs[wid][idx];
            float cf = __int_as_float(p.y);
            const float4 hv = *(const float4*)(hbase + (size_t)p.x * C1);
            acc.x += cf * hv.x; acc.y += cf * hv.y;
            acc.z += cf * hv.z; acc.w += cf * hv.w;
        }
    }
    #pragma unroll
    for (int o = 16; o < 64; o <<= 1) {
        acc.x += __shfl_xor(acc.x, o, 64);
        acc.y += __shfl_xor(acc.y, o, 64);
        acc.z += __shfl_xor(acc.z, o, 64);
        acc.w += __shfl_xor(acc.w, o, 64);
    }
    if (lane < 16)
        *(float4*)(out1 + (size_t)d*C1 + h*HID + c4*4) = acc;
}

// ---------- layer-1: +bias, ELU (in place), BN partial stats ----------
__global__ void k_stats1(float* __restrict__ out, const float* __restrict__ b,
                         float* __restrict__ stats) {
    int c = threadIdx.x;                 // 0..191
    int r0 = blockIdx.x * ROWS1;
    int r1 = min(r0 + ROWS1, N_NODES);
    float bc = b[c];
    float s = 0.f, ss = 0.f;
    for (int r = r0; r < r1; ++r) {
        float v = out[r*C1 + c] + bc;
        v = v > 0.f ? v : expm1f(v);
        out[r*C1 + c] = v;
        s += v; ss += v * v;
    }
    atomicAdd(&stats[c], s);
    atomicAdd(&stats[C1 + c], ss);
}

__global__ void k_fin1(float* __restrict__ stats) {
    int c = threadIdx.x;
    if (c < C1) {
        float mu  = stats[c] / (float)N_NODES;
        float var = stats[C1 + c] / (float)N_NODES - mu * mu;
        stats[2*C1 + c] = mu;
        stats[3*C1 + c] = rsqrtf(var + EPS_BN);
    }
}

__global__ void k_norm1(float* __restrict__ out, const float* __restrict__ g,
                        const float* __restrict__ be, const float* __restrict__ stats) {
    int i = blockIdx.x * blockDim.x + threadIdx.x;
    if (i >= N_NODES * C1) return;
    int c = i % C1;
    out[i] = g[c] * (out[i] - stats[2*C1 + c]) * stats[3*C1 + c] + be[c];
}

// ---------- layer-2 node transform: tiled GEMM [64 nodes x 64 cols]/block ----------
__global__ void __launch_bounds__(256) k_h2(
        const float* __restrict__ h1bn, const float* __restrict__ W2,
        const float* __restrict__ a2s, const float* __restrict__ a2d,
        float* __restrict__ h2, float* __restrict__ asrc, float* __restrict__ adst) {
    __shared__ float As[64 * PAD2];          // ~50 KB
    int tid = threadIdx.x;
    int nb = blockIdx.x * 64;
    const float4* src = (const float4*)(h1bn + (size_t)nb * C1);
    #pragma unroll
    for (int j = 0; j < 12; ++j) {
        int idx = tid + j * 256;             // float4 index 0..3071
        int n = idx / 48, kq = idx - n * 48;
        *(float4*)(As + n * PAD2 + kq * 4) = src[idx];
    }
    __syncthreads();

    int lane = tid & 63;
    int tx = lane & 15, tyw = lane >> 4;
    int ty = (tid >> 6) * 4 + tyw;           // 0..15
    int r0 = ty * 4;                          // A-tile row base (4 nodes)
    const float* wp = W2 + tx * 4;

    float4 acc0 = {0,0,0,0}, acc1 = {0,0,0,0}, acc2 = {0,0,0,0}, acc3 = {0,0,0,0};
    #pragma unroll 4
    for (int k = 0; k < C1; ++k) {
        float4 w4 = *(const float4*)(wp + k * HID);
        float a0 = As[(r0+0)*PAD2 + k];
        float a1 = As[(r0+1)*PAD2 + k];
        float a2 = As[(r0+2)*PAD2 + k];
        float a3 = As[(r0+3)*PAD2 + k];
        acc0.x += a0*w4.x; acc0.y += a0*w4.y; acc0.z += a0*w4.z; acc0.w += a0*w4.w;
        acc1.x += a1*w4.x; acc1.y += a1*w4.y; acc1.z += a1*w4.z; acc1.w += a1*w4.w;
        acc2.x += a2*w4.x; acc2.y += a2*w4.y; acc2.z += a2*w4.z; acc2.w += a2*w4.w;
        acc3.x += a3*w4.x; acc3.y += a3*w4.y; acc3.z += a3*w4.z; acc3.w += a3*w4.w;
    }

    float4 s4 = *(const float4*)(a2s + tx*4);
    float4 d4 = *(const float4*)(a2d + tx*4);

    #define H2_EPI(ACC, I)                                                        \
    {                                                                             \
        int n = nb + r0 + (I);                                                    \
        float s = ACC.x*s4.x + ACC.y*s4.y + ACC.z*s4.z + ACC.w*s4.w;              \
        float d = ACC.x*d4.x + ACC.y*d4.y + ACC.z*d4.z + ACC.w*d4.w;              \
        s += __shfl_xor(s, 1, 64); s += __shfl_xor(s, 2, 64);                     \
        s += __shfl_xor(s, 4, 64); s += __shfl_xor(s, 8, 64);                     \
        d += __shfl_xor(d, 1, 64); d += __shfl_xor(d, 2, 64);                     \
        d += __shfl_xor(d, 4, 64); d += __shfl_xor(d, 8, 64);                     \
        if (n < N_NODES) {                                                        \
            *(float4*)(h2 + (size_t)n*HID + tx*4) = ACC;                          \
            if (tx == 0) { asrc[n] = s; adst[n] = d; }                            \
        }                                                                         \
    }
    H2_EPI(acc0, 0)
    H2_EPI(acc1, 1)
    H2_EPI(acc2, 2)
    H2_EPI(acc3, 3)
    #undef H2_EPI
}

// ---------- layer-2 alpha: thread per CSR slot ----------
__global__ void k_alpha2(const int* __restrict__ srcp, const int* __restrict__ dstp,
                         const float* __restrict__ ae2,
                         const float* __restrict__ asrc, const float* __restrict__ adst,
                         float* __restrict__ alpha2) {
    int j = blockIdx.x * blockDim.x + threadIdx.x;
    if (j >= N_EDGES) return;
    float a = asrc[srcp[j]] + adst[dstp[j]] + ae2[j];
    a = a > 0.f ? a : NEGSL * a;
    alpha2[j] = a;
}

// ---------- layer-2 fused softmax + aggregate: wave per dst, slot-parallel ----------
__global__ void k_agg2(const int* __restrict__ row, const int* __restrict__ srcp,
                       const float* __restrict__ alpha, const float* __restrict__ h2,
                       float* __restrict__ out2) {
    __shared__ int2 pairs[4][64];
    int wid = threadIdx.x >> 6;
    int lane = threadIdx.x & 63;
    int d = blockIdx.x * 4 + wid;
    if (d >= N_NODES) return;
    int r0 = row[d], r1 = row[d + 1];

    float m = -1e30f;
    for (int j = r0 + lane; j < r1; j += 64) m = fmaxf(m, alpha[j]);
    m = wmax(m);

    float ssum = 0.f;
    for (int j = r0 + lane; j < r1; j += 64) ssum += __expf(alpha[j] - m);
    ssum = wred(ssum);
    float inv = 1.f / (ssum + 1e-16f);

    int slot = lane >> 4, c4 = lane & 15;
    const float* hbase = h2 + c4*4;
    float4 acc = make_float4(0.f, 0.f, 0.f, 0.f);
    for (int base = r0; base < r1; base += 64) {
        int n = min(64, r1 - base);
        if (lane < n) {
            float cf = __expf(alpha[base + lane] - m) * inv;
            pairs[wid][lane] = make_int2(srcp[base + lane], __float_as_int(cf));
        }
        #pragma unroll 4
        for (int idx = slot; idx < n; idx += 4) {
            int2 p = pairs[wid][idx];
            float cf = __int_as_float(p.y);
            const float4 hv = *(const float4*)(hbase + (size_t)p.x * HID);
            acc.x += cf * hv.x; acc.y += cf * hv.y;
            acc.z += cf * hv.z; acc.w += cf * hv.w;
        }
    }
    #pragma unroll
    for (int o = 16; o < 64; o <<= 1) {
        acc.x += __shfl_xor(acc.x, o, 64);
        acc.y += __shfl_xor(acc.y, o, 64);
        acc.z += __shfl_xor(acc.z, o, 64);
        acc.w += __shfl_xor(acc.w, o, 64);
    }
    if (lane < 16)
        *(float4*)(out2 + (size_t)d*HID + c4*4) = acc;
}

// ---------- layer-2: +bias, ELU, BN stats (64 cols, 4 row-replicas) ----------
__global__ void k_stats2(float* __restrict__ out, const float* __restrict__ b,
                         float* __restrict__ stats) {
    int c = threadIdx.x & 63;
    int rep = threadIdx.x >> 6;
    int base = blockIdx.x * ROWS2;
    int r1 = min(base + ROWS2, N_NODES);
    float bc = b[c];
    float s = 0.f, ss = 0.f;
    for (int r = base + rep; r < r1; r += 4) {
        float v = out[r*HID + c] + bc;
        v = v > 0.f ? v : expm1f(v);
        out[r*HID + c] = v;
        s += v; ss += v * v;
    }
    __shared__ float ls[256], lss[256];
    ls[threadIdx.x] = s; lss[threadIdx.x] = ss;
    __syncthreads();
    if (rep == 0) {
        s  = ls[c]  + ls[64+c]  + ls[128+c]  + ls[192+c];
        ss = lss[c] + lss[64+c] + lss[128+c] + lss[192+c];
        atomicAdd(&stats[768 + c], s);
        atomicAdd(&stats[832 + c], ss);
    }
}

__global__ void k_fin2(float* __restrict__ stats) {
    int c = threadIdx.x;
    if (c < HID) {
        float mu  = stats[768 + c] / (float)N_NODES;
        float var = stats[832 + c] / (float)N_NODES - mu * mu;
        stats[896 + c] = mu;
        stats[960 + c] = rsqrtf(var + EPS_BN);
    }
}

// ---------- normalize + gate + graph pooling (wave per node) ----------
__global__ void k_final(const float* __restrict__ out2, const float* __restrict__ g,
                        const float* __restrict__ be, const float* __restrict__ stats,
                        const float* __restrict__ wA, const float* __restrict__ bA,
                        const int* __restrict__ batch, float* __restrict__ hg) {
    int n = blockIdx.x * (blockDim.x >> 6) + (threadIdx.x >> 6);
    int lane = threadIdx.x & 63;
    if (n >= N_NODES) return;
    float v = out2[n*HID + lane];
    v = g[lane] * (v - stats[896 + lane]) * stats[960 + lane] + be[lane];
    float gs = wred(v * wA[lane]);
    float gate = 1.f / (1.f + expf(-(gs + bA[0])));
    atomicAdd(&hg[batch[n]*HID + lane], v * gate);
}

// ---------- output GEMMs: [500,64] @ [64,32] x2 ----------
__global__ void k_out(const float* __restrict__ hg, const float* __restrict__ wMu,
                      const float* __restrict__ bMu, const float* __restrict__ wLv,
                      const float* __restrict__ bLv, float* __restrict__ out) {
    __shared__ float rowv[HID];
    int gid = blockIdx.x, t = threadIdx.x;
    rowv[t] = hg[gid*HID + t];
    __syncthreads();
    if (t < LATD) {
        float s = 0.f;
        #pragma unroll
        for (int k = 0; k < HID; ++k) s += rowv[k] * wMu[k*LATD + t];
        out[gid*LATD + t] = s + bMu[t];
    } else {
        int c = t - LATD;
        float s = 0.f;
        #pragma unroll
        for (int k = 0; k < HID; ++k) s += rowv[k] * wLv[k*LATD + c];
        out[NGRAPH*LATD + gid*LATD + c] = s + bLv[c];
    }
}

extern "C" void kernel_launch(void* const* d_in, const int* in_sizes, int n_in,
                              void* d_out, int out_size, void* d_ws, size_t ws_size,
                              hipStream_t stream) {
    const float* x   = (const float*)d_in[0];
    const int*   ei  = (const int*)  d_in[1];
    const float* ea  = (const float*)d_in[2];
    const int*   bat = (const int*)  d_in[3];
    const float* W1  = (const float*)d_in[4];
    const float* a1s = (const float*)d_in[5];
    const float* a1d = (const float*)d_in[6];
    const float* We1 = (const float*)d_in[7];
    const float* a1e = (const float*)d_in[8];
    const float* b1  = (const float*)d_in[9];
    const float* g1  = (const float*)d_in[10];
    const float* be1 = (const float*)d_in[11];
    const float* W2  = (const float*)d_in[12];
    const float* a2s = (const float*)d_in[13];
    const float* a2d = (const float*)d_in[14];
    const float* We2 = (const float*)d_in[15];
    const float* a2e = (const float*)d_in[16];
    const float* b2  = (const float*)d_in[17];
    const float* g2  = (const float*)d_in[18];
    const float* be2 = (const float*)d_in[19];
    const float* wA  = (const float*)d_in[20];
    const float* bA  = (const float*)d_in[21];
    const float* wMu = (const float*)d_in[22];
    const float* bMu = (const float*)d_in[23];
    const float* wLv = (const float*)d_in[24];
    const float* bLv = (const float*)d_in[25];
    float* out = (float*)d_out;
    float* w = (float*)d_ws;

    // ---- workspace layout (floats) ----
    const size_t oH1   = 0;                             // h1 [N*192]; later h2 [N*64]
    const size_t oO1   = oH1  + (size_t)N_NODES*C1;     // out1 [N*192]; later out2 [N*64]
    const size_t oAS   = oO1  + (size_t)N_NODES*C1;     // asrc [N*3] (layer2: [N])
    const size_t oAD   = oAS  + (size_t)N_NODES*H1;     // adst [N*3]
    const size_t oSRC  = oAD  + (size_t)N_NODES*H1;     // srcp [E] int
    const size_t oDST  = oSRC + (size_t)N_EDGES;        // dstp [E] int
    const size_t oAE2  = oDST + (size_t)N_EDGES;        // ae2 [E]
    const size_t oAL   = oAE2 + (size_t)N_EDGES;        // alpha1 [3E] (layer2: [E] plane0)
    const size_t oROW  = oAL  + (size_t)N_EDGES*H1;     // row [N+1] int
    const size_t oCUR  = oROW + (size_t)(N_NODES+1);    // cursor [N] int
    const size_t oPERM = oCUR + (size_t)N_NODES;        // eperm [E] int
    const size_t oBSUM = oPERM+ (size_t)N_EDGES;        // bsum [NSBLK] int
    const size_t oBOFF = oBSUM+ (size_t)NSBLK;          // boff [NSBLK] int
    const size_t Z0raw = oBOFF+ (size_t)NSBLK;
    const size_t Z0    = (Z0raw + 3) & ~(size_t)3;      // 16B-align (int2/int4 loads on deg)
    const size_t oDEG  = Z0;                            // deg [N] int
    const size_t oST   = oDEG + (size_t)N_NODES;        // stats [1024]
    const size_t oHG   = oST  + 1024;                   // hg [500*64]
    const size_t oV    = oHG  + (size_t)NGRAPH*HID;     // V [16] (pad 64)
    const size_t oEND  = oV   + 64;

    hipMemsetAsync(w + Z0, 0, (oEND - Z0) * sizeof(float), stream);

    k_v<<<1, 64, 0, stream>>>(We1, a1e, We2, a2e, w + oV);
    k_h1att<<<(N_NODES*H1 + 3)/4, 256, 0, stream>>>(x, W1, a1s, a1d,
                                                    w + oH1, w + oAS, w + oAD);
    k_deg<<<(N_EDGES + 255)/256, 256, 0, stream>>>(ei, (int*)(w + oDEG));
    k_scanA<<<NSBLK, 256, 0, stream>>>((int*)(w + oDEG), (int*)(w + oBSUM));
    k_scanB<<<1, 128, 0, stream>>>((int*)(w + oBSUM), (int*)(w + oBOFF), (int*)(w + oROW));
    k_scanC<<<NSBLK, 256, 0, stream>>>((int*)(w + oDEG), (int*)(w + oBOFF),
                                       (int*)(w + oROW), (int*)(w + oCUR));
    k_perm<<<(N_EDGES + 255)/256, 256, 0, stream>>>(ei, (int*)(w + oCUR), (int*)(w + oPERM));
    k_fill2<<<(N_EDGES + 255)/256, 256, 0, stream>>>(ei, ea, (int*)(w + oPERM),
                                                     w + oAS, w + oAD, w + oV,
                                                     (int*)(w + oSRC), (int*)(w + oDST),
                                                     w + oAL, w + oAE2);

    k_agg1<<<(N_NODES*H1 + 3)/4, 256, 0, stream>>>((int*)(w + oROW), (int*)(w + oSRC),
                                                   w + oAL, w + oH1, w + oO1);
    k_stats1<<<(N_NODES + ROWS1 - 1)/ROWS1, C1, 0, stream>>>(w + oO1, b1, w + oST);
    k_fin1<<<1, C1, 0, stream>>>(w + oST);
    k_norm1<<<(N_NODES*C1 + 255)/256, 256, 0, stream>>>(w + oO1, g1, be1, w + oST);

    k_h2<<<(N_NODES + 63)/64, 256, 0, stream>>>(w + oO1, W2, a2s, a2d,
                                                w + oH1, w + oAS, w + oAD);
    k_alpha2<<<(N_EDGES + 255)/256, 256, 0, stream>>>((int*)(w + oSRC), (int*)(w + oDST),
                                                      w + oAE2, w + oAS, w + oAD, w + oAL);
    k_agg2<<<(N_NODES + 3)/4, 256, 0, stream>>>((int*)(w + oROW), (int*)(w + oSRC),
                                                w + oAL, w + oH1, w + oO1);
    k_stats2<<<(N_NODES + ROWS2 - 1)/ROWS2, 256, 0, stream>>>(w + oO1, b2, w + oST);
    k_fin2<<<1, HID, 0, stream>>>(w + oST);
    k_final<<<(N_NODES + 3)/4, 256, 0, stream>>>(w + oO1, g2, be2, w + oST, wA, bA, bat, w + oHG);
    k_out<<<NGRAPH, HID, 0, stream>>>(w + oHG, wMu, bMu, wLv, bLv, out);
}